// Round 13
// baseline (137.330 us; speedup 1.0000x reference)
//
#include <hip/hip_runtime.h>
#include <hip/hip_bf16.h>
#include <math.h>

#define NQ 6144
#define MR 6144
#define DIN 16
#define HID 256
#define INV_T 10.0f

typedef __attribute__((ext_vector_type(4))) float f32x4;
typedef __attribute__((ext_vector_type(8))) short bf16x8;

// Packed fragment-major operand layout (shorts):
//   pk[group][kc][l15][ksub*8 + j], group = row/16, kc = k/32, ksub = (k%32)/8
//   short offset = group*4096 + kc*512 + l15*32 + ksub*8

static __device__ __forceinline__ unsigned short f2bf(float f) {
  __hip_bfloat16 h = __float2bfloat16(f);
  return __builtin_bit_cast(unsigned short, h);
}

// async global->LDS, 16 B per lane. LDS base must be wave-uniform.
static __device__ __forceinline__ void gload16(const void* g, void* l) {
  __builtin_amdgcn_global_load_lds(
      (const __attribute__((address_space(1))) unsigned int*)g,
      (__attribute__((address_space(3))) unsigned int*)l, 16, 0, 0);
}

// ---------------------------------------------------------------------------
// K0: prep — W2 -> bf16, Wb -> bf16 transposed; zero the atomic sum tables.
// ---------------------------------------------------------------------------
__global__ __launch_bounds__(256) void k_prep(
    const float* __restrict__ W2, const float* __restrict__ Wb,
    unsigned short* __restrict__ W2bf, unsigned short* __restrict__ Wbt,
    float* __restrict__ rowS, float* __restrict__ colS)
{
  const int idx = blockIdx.x * 256 + threadIdx.x;  // = j*256 + c
  W2bf[idx] = f2bf(W2[idx]);
  const int j = idx >> 8, c = idx & 255;
  Wbt[(size_t)c * 256 + j] = f2bf(Wb[idx]);
  if (idx < NQ) rowS[idx] = 0.0f;
  else if (idx < NQ + MR) colS[idx - NQ] = 0.0f;
}

// ---------------------------------------------------------------------------
// K1: compress (MFMA). 16 rows/block = one packed group, 256 thr (4 waves).
// ---------------------------------------------------------------------------
__global__ __launch_bounds__(256) void k_compress(
    const float* __restrict__ q, const float* __restrict__ ret,
    const float* __restrict__ W1, const float* __restrict__ b1,
    const unsigned short* __restrict__ W2bf, const float* __restrict__ b2,
    const unsigned short* __restrict__ Wbt,
    unsigned short* __restrict__ Apk, unsigned short* __restrict__ Bpk)
{
  const int tid = threadIdx.x;
  const bool is_q = blockIdx.x < (NQ / 16);
  const int grp = is_q ? blockIdx.x : blockIdx.x - NQ / 16;
  const int row0 = grp * 16;
  const float* x = is_q ? q : ret;

  __shared__ float xs[16][DIN];
  __shared__ __align__(16) unsigned short tb[16 * 256];
  __shared__ __align__(16) unsigned short hb[16 * 256];

  ((float*)xs)[tid] = x[(size_t)row0 * DIN + tid];
  __syncthreads();

  // ---- phase 1: gelu(x@W1^T + b1) -> tb (bf16, swizzled) ----
  {
    float w[DIN];
#pragma unroll
    for (int d = 0; d < DIN; ++d) w[d] = W1[tid * DIN + d];
    const float bb = b1[tid];
#pragma unroll
    for (int rr = 0; rr < 16; ++rr) {
      float a = bb;
#pragma unroll
      for (int d = 0; d < DIN; ++d) a += xs[rr][d] * w[d];
      a = 0.5f * a * (1.0f + erff(a * 0.70710678118654752f));
      tb[rr * 256 + (tid ^ ((rr & 7) << 3))] = f2bf(a);
    }
  }
  __syncthreads();

  const int wid = tid >> 6, lane = tid & 63;
  const int l15 = lane & 15;
  const int lk = (lane >> 4) * 8;

  // ---- phase 2: h = t @ W2^T + b2 -> hb ----
  {
    f32x4 acc[4];
#pragma unroll
    for (int ci = 0; ci < 4; ++ci) acc[ci] = (f32x4)0.0f;

    for (int kk = 0; kk < HID; kk += 32) {
      const bf16x8 a = *(const bf16x8*)&tb[l15 * 256 + ((kk + lk) ^ ((l15 & 7) << 3))];
#pragma unroll
      for (int ci = 0; ci < 4; ++ci) {
        const int bc = wid * 64 + ci * 16 + l15;
        const bf16x8 b = *(const bf16x8*)&W2bf[(size_t)bc * HID + kk + lk];
        acc[ci] = __builtin_amdgcn_mfma_f32_16x16x32_bf16(a, b, acc[ci], 0, 0, 0);
      }
    }

#pragma unroll
    for (int ci = 0; ci < 4; ++ci) {
      const int col = wid * 64 + ci * 16 + l15;
      const float bb2 = b2[col];
#pragma unroll
      for (int qq = 0; qq < 4; ++qq) {
        const int row = (lane >> 4) * 4 + qq;
        hb[row * 256 + (col ^ ((row & 7) << 3))] = f2bf(acc[ci][qq] + bb2);
      }
    }
  }
  __syncthreads();

  if (!is_q) {
#pragma unroll
    for (int i = 0; i < 2; ++i) {
      const int u = i * 256 + tid;
      const int kc = u >> 6, lr = (u >> 2) & 15, ks = u & 3;
      const int k = kc * 32 + ks * 8;
      const bf16x8 v = *(const bf16x8*)&hb[lr * 256 + (k ^ ((lr & 7) << 3))];
      *(bf16x8*)&Bpk[(size_t)grp * 4096 + (size_t)u * 8] = v;
    }
    return;
  }

  // ---- phase 3 (q only): g = h @ Wb ----
  {
    f32x4 acc[4];
#pragma unroll
    for (int ci = 0; ci < 4; ++ci) acc[ci] = (f32x4)0.0f;

    for (int kk = 0; kk < HID; kk += 32) {
      const bf16x8 a = *(const bf16x8*)&hb[l15 * 256 + ((kk + lk) ^ ((l15 & 7) << 3))];
#pragma unroll
      for (int ci = 0; ci < 4; ++ci) {
        const int bc = wid * 64 + ci * 16 + l15;
        const bf16x8 b = *(const bf16x8*)&Wbt[(size_t)bc * HID + kk + lk];
        acc[ci] = __builtin_amdgcn_mfma_f32_16x16x32_bf16(a, b, acc[ci], 0, 0, 0);
      }
    }

#pragma unroll
    for (int ci = 0; ci < 4; ++ci) {
      const int col = wid * 64 + ci * 16 + l15;
#pragma unroll
      for (int qq = 0; qq < 4; ++qq) {
        const int row = (lane >> 4) * 4 + qq;
        tb[row * 256 + (col ^ ((row & 7) << 3))] = f2bf(acc[ci][qq]);
      }
    }
  }
  __syncthreads();

#pragma unroll
  for (int i = 0; i < 2; ++i) {
    const int u = i * 256 + tid;
    const int kc = u >> 6, lr = (u >> 2) & 15, ks = u & 3;
    const int k = kc * 32 + ks * 8;
    const bf16x8 v = *(const bf16x8*)&tb[lr * 256 + (k ^ ((lr & 7) << 3))];
    *(bf16x8*)&Apk[(size_t)grp * 4096 + (size_t)u * 8] = v;
  }
}

// ---------------------------------------------------------------------------
// K2: logits = g @ hr^T + b_bil. 256x128 tile, 8 waves (4x2), 512 thr,
// dbuf LDS via global_load_lds. 2D-REGION XCD swizzle: the 24x48 tile grid
// splits into 8 regions of 12x12 (one per XCD); region working set =
// 1.5 MB A + 0.75 MB B — both fit the 4 MB per-XCD L2, so staged loads are
// L2 hits after the first sweep. Cached logF stores (L3-resident for k_final).
// Epilogue: no-max exp sums accumulated via device-scope atomicAdd.
// ---------------------------------------------------------------------------
__global__ __launch_bounds__(512, 4) void k_gemm(
    const unsigned short* __restrict__ Apk,
    const unsigned short* __restrict__ Bpk,
    const float* __restrict__ b_bil,
    float* __restrict__ logF,
    float* __restrict__ rowS,    // [NQ] atomic exp-sum
    float* __restrict__ colS)    // [MR] atomic exp-sum
{
  const int tid = threadIdx.x;
  const int wid = tid >> 6, lane = tid & 63;
  const int wr = wid >> 1, wc = wid & 1;       // 4 row-waves x 2 col-waves

  // 2D-region XCD swizzle: xcd = orig&7 owns region (xcd>>2, xcd&3) of the
  // 2x4 region grid; within region, idx = orig>>3 in [0,144), cc fastest.
  const int orig = blockIdx.y * 48 + blockIdx.x;
  const int xcd = orig & 7;
  const int idx = orig >> 3;                   // [0,144)
  const int rr_ = idx / 12, cc_ = idx % 12;
  const int brow = ((xcd >> 2) * 12 + rr_) * 256;  // [0,24) 256-row tiles
  const int bcol = ((xcd & 3) * 12 + cc_) * 128;   // [0,48) 128-col tiles
  const int brow16 = brow >> 4, bcol16 = bcol >> 4;

  __shared__ __align__(16) unsigned short As[2][8192];  // 16 groups x 1KB
  __shared__ __align__(16) unsigned short Bs[2][4096];  //  8 groups x 1KB

  const int l15 = lane & 15;
  const int ksg = lane >> 4;

  f32x4 acc[4][4];
#pragma unroll
  for (int i = 0; i < 4; ++i)
#pragma unroll
    for (int j = 0; j < 4; ++j) acc[i][j] = (f32x4)0.0f;

  // stage kc=0: wave w loads A groups 2w,2w+1 and B group w (1 KB each)
  gload16(Apk + (size_t)(brow16 + 2 * wid) * 4096 + lane * 8,
          &As[0][(2 * wid) * 512]);
  gload16(Apk + (size_t)(brow16 + 2 * wid + 1) * 4096 + lane * 8,
          &As[0][(2 * wid + 1) * 512]);
  gload16(Bpk + (size_t)(bcol16 + wid) * 4096 + lane * 8, &Bs[0][wid * 512]);

  int cur = 0;
  for (int kc = 0; kc < 8; ++kc) {
    __syncthreads();  // drains vmcnt (buf[cur] staged) + lgkm (prev reads)
    if (kc < 7) {
      const int kn = (kc + 1) * 512;
      gload16(Apk + (size_t)(brow16 + 2 * wid) * 4096 + kn + lane * 8,
              &As[cur ^ 1][(2 * wid) * 512]);
      gload16(Apk + (size_t)(brow16 + 2 * wid + 1) * 4096 + kn + lane * 8,
              &As[cur ^ 1][(2 * wid + 1) * 512]);
      gload16(Bpk + (size_t)(bcol16 + wid) * 4096 + kn + lane * 8,
              &Bs[cur ^ 1][wid * 512]);
    }
    const int fo = l15 * 32 + ksg * 8;
    bf16x8 a[4], b[4];
#pragma unroll
    for (int mi = 0; mi < 4; ++mi)
      a[mi] = *(const bf16x8*)&As[cur][(wr * 4 + mi) * 512 + fo];
#pragma unroll
    for (int ni = 0; ni < 4; ++ni)
      b[ni] = *(const bf16x8*)&Bs[cur][(wc * 4 + ni) * 512 + fo];
#pragma unroll
    for (int mi = 0; mi < 4; ++mi)
#pragma unroll
      for (int ni = 0; ni < 4; ++ni)
        acc[mi][ni] = __builtin_amdgcn_mfma_f32_16x16x32_bf16(
            a[mi], b[ni], acc[mi][ni], 0, 0, 0);
    cur ^= 1;
  }

  const float bb = b_bil[0];
#pragma unroll
  for (int mi = 0; mi < 4; ++mi)
#pragma unroll
    for (int ni = 0; ni < 4; ++ni)
#pragma unroll
      for (int qq = 0; qq < 4; ++qq) acc[mi][ni][qq] += bb;

  const int r0 = brow + wr * 64 + ksg * 4;
  const int c0 = bcol + wc * 64 + l15;
#pragma unroll
  for (int mi = 0; mi < 4; ++mi)
#pragma unroll
    for (int qq = 0; qq < 4; ++qq) {
      const int rr = r0 + mi * 16 + qq;
#pragma unroll
      for (int ni = 0; ni < 4; ++ni)
        logF[(size_t)rr * MR + c0 + ni * 16] = acc[mi][ni][qq];  // cached store
    }

  // ---- no-max exp sums, accumulated with device-scope atomics ----
  float csum[4] = {0.0f, 0.0f, 0.0f, 0.0f};
#pragma unroll
  for (int mi = 0; mi < 4; ++mi) {
#pragma unroll
    for (int qq = 0; qq < 4; ++qq) {
      float rsum = 0.0f;
#pragma unroll
      for (int ni = 0; ni < 4; ++ni) {
        const float e = __expf(acc[mi][ni][qq] * INV_T);
        rsum += e;
        csum[ni] += e;
      }
      rsum += __shfl_xor(rsum, 1);
      rsum += __shfl_xor(rsum, 2);
      rsum += __shfl_xor(rsum, 4);
      rsum += __shfl_xor(rsum, 8);
      if (l15 == 0) atomicAdd(&rowS[r0 + mi * 16 + qq], rsum);
    }
  }
#pragma unroll
  for (int ni = 0; ni < 4; ++ni) {
    csum[ni] += __shfl_xor(csum[ni], 16);
    csum[ni] += __shfl_xor(csum[ni], 32);
  }
  if (lane < 16) {
#pragma unroll
    for (int ni = 0; ni < 4; ++ni)
      atomicAdd(&colS[bcol + wc * 64 + ni * 16 + lane], csum[ni]);
  }
}

// ---------------------------------------------------------------------------
// K3: pi = exp(l*10) * (0.5/(rowS+es) + 0.5/(colS+es)). logF read is L3-hit
// (cached store in k_gemm); pi NT-stored (never re-read). 8 floats/thread.
// Slack terms folded in here — no separate combine kernel.
// ---------------------------------------------------------------------------
__global__ __launch_bounds__(256) void k_final(
    const float* __restrict__ logF,
    const float* __restrict__ rowS, const float* __restrict__ colS,
    const float* __restrict__ slack_q, const float* __restrict__ slack_ret,
    float* __restrict__ out_pi)
{
  const int row = blockIdx.x / 3;
  const int seg = blockIdx.x % 3;
  const int col = seg * 2048 + threadIdx.x * 8;
  const size_t base = (size_t)row * MR + col;

  const float esq = __expf(slack_q[0] * INV_T);
  const float esr = __expf(slack_ret[0] * INV_T);
  const float rinv = 0.5f / (rowS[row] + esq);

  const f32x4 cs0 = *(const f32x4*)(colS + col);
  const f32x4 cs1 = *(const f32x4*)(colS + col + 4);
  const f32x4 l0 = *(const f32x4*)(logF + base);
  const f32x4 l1 = *(const f32x4*)(logF + base + 4);

  f32x4 o0, o1;
  o0.x = __expf(l0.x * INV_T) * (rinv + 0.5f / (cs0.x + esr));
  o0.y = __expf(l0.y * INV_T) * (rinv + 0.5f / (cs0.y + esr));
  o0.z = __expf(l0.z * INV_T) * (rinv + 0.5f / (cs0.z + esr));
  o0.w = __expf(l0.w * INV_T) * (rinv + 0.5f / (cs0.w + esr));
  o1.x = __expf(l1.x * INV_T) * (rinv + 0.5f / (cs1.x + esr));
  o1.y = __expf(l1.y * INV_T) * (rinv + 0.5f / (cs1.y + esr));
  o1.z = __expf(l1.z * INV_T) * (rinv + 0.5f / (cs1.z + esr));
  o1.w = __expf(l1.w * INV_T) * (rinv + 0.5f / (cs1.w + esr));
  __builtin_nontemporal_store(o0, (f32x4*)(out_pi + base));
  __builtin_nontemporal_store(o1, (f32x4*)(out_pi + base + 4));
}

// ---------------------------------------------------------------------------
extern "C" void kernel_launch(void* const* d_in, const int* in_sizes, int n_in,
                              void* d_out, int out_size, void* d_ws, size_t ws_size,
                              hipStream_t stream) {
  const float* q  = (const float*)d_in[0];
  const float* r  = (const float*)d_in[1];
  const float* W1 = (const float*)d_in[2];
  const float* b1 = (const float*)d_in[3];
  const float* W2 = (const float*)d_in[4];
  const float* b2 = (const float*)d_in[5];
  const float* Wb = (const float*)d_in[6];
  const float* bb = (const float*)d_in[7];
  const float* sq = (const float*)d_in[8];
  const float* sr = (const float*)d_in[9];

  float* out_pi = (float*)d_out;                      // [NQ][MR] f32
  float* out_lg = out_pi + (size_t)NQ * MR;           // [NQ][MR] f32 logits

  char* w = (char*)d_ws;
  size_t off = 0;
  auto alloc = [&](size_t bytes) {
    void* p = w + off;
    off += (bytes + 255) & ~(size_t)255;
    return p;
  };
  unsigned short* Apk  = (unsigned short*)alloc((size_t)NQ * HID * 2);
  unsigned short* Bpk  = (unsigned short*)alloc((size_t)MR * HID * 2);
  unsigned short* W2bf = (unsigned short*)alloc((size_t)HID * HID * 2);
  unsigned short* Wbt  = (unsigned short*)alloc((size_t)HID * HID * 2);
  float* rowS = (float*)alloc((size_t)NQ * 4);
  float* colS = (float*)alloc((size_t)MR * 4);

  k_prep<<<dim3(HID * HID / 256), 256, 0, stream>>>(W2, Wb, W2bf, Wbt,
                                                    rowS, colS);
  k_compress<<<dim3((NQ + MR) / 16), 256, 0, stream>>>(q, r, W1, b1, W2bf, b2,
                                                       Wbt, Apk, Bpk);
  k_gemm<<<dim3(48, 24), 512, 0, stream>>>(Apk, Bpk, bb, out_lg, rowS, colS);
  k_final<<<dim3(NQ * 3), 256, 0, stream>>>(out_lg, rowS, colS, sq, sr,
                                            out_pi);
}